// Round 3
// baseline (240.082 us; speedup 1.0000x reference)
//
#include <hip/hip_runtime.h>
#include <hip/hip_bf16.h>
#include <cfloat>
#include <climits>
#include <cmath>

// Problem constants: B=32, S=2048, H=1024, K=4, PREV=2, R=8
#define BB 32
#define SS 2048
#define HH 1024
#define KK 4
#define CH 32  // s-chunks per batch row in fused_attn (64 rows each)

// ---------------------------------------------------------------------------
// gates partials: part[(kc*32 + b)*6144 + j] = sum_{k in chunk} A[b,k]*W[j,k]
// j in [0,3072): W_ih with A=x ; j in [3072,6144): W_hh with A=h_old
// grid (12, 16), block 256. Thread: rows j0+2t, j0+2t+1; k-chunk = 64.
// A reads are wave-uniform -> scalar (SGPR) loads; W reads stream from L1/L2.
// No LDS at all.
// ---------------------------------------------------------------------------
__global__ __launch_bounds__(256) void gates_partial(
    const float* __restrict__ x, const float* __restrict__ h_old,
    const float* __restrict__ W_ih, const float* __restrict__ W_hh,
    float* __restrict__ part) {
  int t = threadIdx.x;
  int jb = blockIdx.x;       // 0..11
  int k0 = blockIdx.y * 64;  // k-chunk base
  bool second = (jb >= 6);
  const float* A = second ? h_old : x;
  const float* W = second ? W_hh : W_ih;
  int j0 = jb * 512;                  // global j base
  int jr = j0 - (second ? 3072 : 0);  // row base within W
  const float* w1p = W + (size_t)(jr + 2 * t) * HH + k0;
  const float* w2p = w1p + HH;
  float acc0[32], acc1[32];
#pragma unroll
  for (int b = 0; b < 32; b++) { acc0[b] = 0.f; acc1[b] = 0.f; }
  for (int kk = 0; kk < 64; kk += 4) {
    float4 w1 = *(const float4*)(w1p + kk);
    float4 w2 = *(const float4*)(w2p + kk);
#pragma unroll
    for (int b = 0; b < 32; b++) {
      float4 a = *(const float4*)(A + (size_t)b * HH + k0 + kk);  // uniform
      acc0[b] += a.x * w1.x + a.y * w1.y + a.z * w1.z + a.w * w1.w;
      acc1[b] += a.x * w2.x + a.y * w2.y + a.z * w2.z + a.w * w2.w;
    }
  }
  float* pb = part + (size_t)blockIdx.y * 32 * 6144 + j0 + 2 * t;
#pragma unroll
  for (int b = 0; b < 32; b++) {
    *(float2*)(pb + (size_t)b * 6144) = make_float2(acc0[b], acc1[b]);
  }
}

// ---------------------------------------------------------------------------
// Reduce gate partials (16 k-chunks) + bias + GRU pointwise -> h_new
// grid 128 (b = blk>>2, h-tile = blk&3), block 256
// ---------------------------------------------------------------------------
__global__ __launch_bounds__(256) void gates_reduce_gru(
    const float* __restrict__ part, const float* __restrict__ b_ih,
    const float* __restrict__ b_hh, const float* __restrict__ h_old,
    float* __restrict__ h_new) {
  int t = threadIdx.x;
  int b = blockIdx.x >> 2;
  int h = (blockIdx.x & 3) * 256 + t;
  float s0 = 0.f, s1 = 0.f, s2 = 0.f, s3 = 0.f, s4 = 0.f, s5 = 0.f;
#pragma unroll
  for (int kc = 0; kc < 16; kc++) {
    const float* p = part + ((size_t)kc * 32 + b) * 6144;
    s0 += p[h];
    s1 += p[1024 + h];
    s2 += p[2048 + h];
    s3 += p[3072 + h];
    s4 += p[4096 + h];
    s5 += p[5120 + h];
  }
  float ir = s0 + b_ih[h], iz = s1 + b_ih[1024 + h], in_ = s2 + b_ih[2048 + h];
  float hr = s3 + b_hh[h], hz = s4 + b_hh[1024 + h], hn = s5 + b_hh[2048 + h];
  float r = 1.f / (1.f + expf(-(ir + hr)));
  float z = 1.f / (1.f + expf(-(iz + hz)));
  float n = tanhf(in_ + r * hn);
  h_new[b * HH + h] = (1.f - z) * n + z * h_old[b * HH + h];
}

// ---------------------------------------------------------------------------
// qpart[(kc*32+b)*1024 + n] = sum_{k in chunk64} h_new[b,k] * Wk[k*H + n]
// grid (4, 16), block 256. Wk reads coalesced (lane-per-n); h_new uniform.
// ---------------------------------------------------------------------------
__global__ __launch_bounds__(256) void q_partial(const float* __restrict__ hnew,
                                                 const float* __restrict__ Wk,
                                                 float* __restrict__ qpart) {
  int n = blockIdx.x * 256 + threadIdx.x;
  int k0 = blockIdx.y * 64;
  float acc[32];
#pragma unroll
  for (int b = 0; b < 32; b++) acc[b] = 0.f;
  for (int kk = 0; kk < 64; kk += 4) {
    int k = k0 + kk;
    float w0 = Wk[(size_t)k * HH + n];
    float w1 = Wk[(size_t)(k + 1) * HH + n];
    float w2 = Wk[(size_t)(k + 2) * HH + n];
    float w3 = Wk[(size_t)(k + 3) * HH + n];
#pragma unroll
    for (int b = 0; b < 32; b++) {
      float4 a = *(const float4*)(hnew + (size_t)b * HH + k);  // uniform
      acc[b] += a.x * w0 + a.y * w1 + a.z * w2 + a.w * w3;
    }
  }
  float* pb = qpart + (size_t)blockIdx.y * 32 * 1024 + n;
#pragma unroll
  for (int b = 0; b < 32; b++) pb[(size_t)b * 1024] = acc[b];
}

// blocks 0..127: q = sum of 16 k-chunk partials. block 128: hbk[b] = h_new[b].bk
__global__ __launch_bounds__(256) void q_reduce_hbk(
    const float* __restrict__ qpart, const float* __restrict__ hnew,
    const float* __restrict__ bk, float* __restrict__ q,
    float* __restrict__ hbk) {
  int t = threadIdx.x;
  if (blockIdx.x < 128) {
    int b = blockIdx.x >> 2;
    int n = (blockIdx.x & 3) * 256 + t;
    float s = 0.f;
#pragma unroll
    for (int kc = 0; kc < 16; kc++) s += qpart[((size_t)kc * 32 + b) * 1024 + n];
    q[b * HH + n] = s;
  } else {
    __shared__ float red[256];
    for (int b = 0; b < BB; b++) {
      float s = 0.f;
      for (int k = t; k < HH; k += 256) s += hnew[b * HH + k] * bk[k];
      red[t] = s;
      __syncthreads();
      for (int o = 128; o; o >>= 1) {
        if (t < o) red[t] += red[t + o];
        __syncthreads();
      }
      if (t == 0) hbk[b] = red[0];
      __syncthreads();
    }
  }
}

// ---------------------------------------------------------------------------
// Fused attention pass (single HBM read of eo), per-wave independent rows:
// wave w of block (sc,b) handles rows sc*64 + w*16 .. +15, 4 rows per tile.
// Full-row dot per lane-slice + 6-step butterfly (all lanes get the value),
// online softmax accumulate into per-lane h-slice registers.
// Block end: combine 4 waves' (m,sum,acc) via LDS -> c0part, msum_part.
// ---------------------------------------------------------------------------
__global__ __launch_bounds__(256) void fused_attn(
    const float* __restrict__ eo, const float* __restrict__ q,
    const float* __restrict__ hbk, const float* __restrict__ mask,
    float* __restrict__ logits, float* __restrict__ c0part,
    float* __restrict__ msum_part) {
  __shared__ float cacc[4][1024];
  __shared__ float cms[4][2];
  int b = blockIdx.y, sc = blockIdx.x, t = threadIdx.x;
  int w = t >> 6, lane = t & 63;
  const float4* q4 = (const float4*)(q + (size_t)b * HH);
  float4 qv[4];
#pragma unroll
  for (int i = 0; i < 4; i++) qv[i] = q4[i * 64 + lane];
  float hb = hbk[b];
  float m = -FLT_MAX, sum = 0.f;
  float4 acc[4];
#pragma unroll
  for (int i = 0; i < 4; i++) acc[i] = make_float4(0.f, 0.f, 0.f, 0.f);
  int rbase = sc * 64 + w * 16;
  for (int tile = 0; tile < 4; tile++) {
    int r0 = rbase + tile * 4;
    float4 rv[4][4];
#pragma unroll
    for (int rr = 0; rr < 4; rr++) {
      const float4* e4 = (const float4*)(eo + ((size_t)b * SS + r0 + rr) * HH);
#pragma unroll
      for (int i = 0; i < 4; i++) rv[rr][i] = e4[i * 64 + lane];
    }
    float p[4];
#pragma unroll
    for (int rr = 0; rr < 4; rr++) {
      float s = 0.f;
#pragma unroll
      for (int i = 0; i < 4; i++) {
        s += rv[rr][i].x * qv[i].x + rv[rr][i].y * qv[i].y +
             rv[rr][i].z * qv[i].z + rv[rr][i].w * qv[i].w;
      }
      p[rr] = s;
    }
#pragma unroll
    for (int off = 32; off; off >>= 1) {
#pragma unroll
      for (int rr = 0; rr < 4; rr++) p[rr] += __shfl_xor(p[rr], off);
    }
    float lv[4];
#pragma unroll
    for (int rr = 0; rr < 4; rr++)
      lv[rr] = (p[rr] + hb) * 0.03125f + mask[(size_t)b * SS + r0 + rr];
    if (lane == 0) {
#pragma unroll
      for (int rr = 0; rr < 4; rr++) logits[(size_t)b * SS + r0 + rr] = lv[rr];
    }
    float mt = fmaxf(fmaxf(lv[0], lv[1]), fmaxf(lv[2], lv[3]));
    float m_new = fmaxf(m, mt);
    float scale = expf(m - m_new);  // exp(-inf)=0 on first tile
    float wg[4];
#pragma unroll
    for (int rr = 0; rr < 4; rr++) wg[rr] = expf(lv[rr] - m_new);
    sum = sum * scale + wg[0] + wg[1] + wg[2] + wg[3];
#pragma unroll
    for (int i = 0; i < 4; i++) {
      acc[i].x = acc[i].x * scale + wg[0] * rv[0][i].x + wg[1] * rv[1][i].x +
                 wg[2] * rv[2][i].x + wg[3] * rv[3][i].x;
      acc[i].y = acc[i].y * scale + wg[0] * rv[0][i].y + wg[1] * rv[1][i].y +
                 wg[2] * rv[2][i].y + wg[3] * rv[3][i].y;
      acc[i].z = acc[i].z * scale + wg[0] * rv[0][i].z + wg[1] * rv[1][i].z +
                 wg[2] * rv[2][i].z + wg[3] * rv[3][i].z;
      acc[i].w = acc[i].w * scale + wg[0] * rv[0][i].w + wg[1] * rv[1][i].w +
                 wg[2] * rv[2][i].w + wg[3] * rv[3][i].w;
    }
    m = m_new;
  }
  // block combine (one sync)
#pragma unroll
  for (int i = 0; i < 4; i++)
    *(float4*)&cacc[w][i * 256 + lane * 4] = acc[i];
  if (lane == 0) { cms[w][0] = m; cms[w][1] = sum; }
  __syncthreads();
  float m0 = cms[0][0], m1 = cms[1][0], m2 = cms[2][0], m3 = cms[3][0];
  float mb = fmaxf(fmaxf(m0, m1), fmaxf(m2, m3));
  float wt0 = expf(m0 - mb), wt1 = expf(m1 - mb), wt2 = expf(m2 - mb),
        wt3 = expf(m3 - mb);
  float sb = cms[0][1] * wt0 + cms[1][1] * wt1 + cms[2][1] * wt2 + cms[3][1] * wt3;
  float4 a0 = *(float4*)&cacc[0][4 * t];
  float4 a1 = *(float4*)&cacc[1][4 * t];
  float4 a2 = *(float4*)&cacc[2][4 * t];
  float4 a3 = *(float4*)&cacc[3][4 * t];
  float4 r;
  r.x = wt0 * a0.x + wt1 * a1.x + wt2 * a2.x + wt3 * a3.x;
  r.y = wt0 * a0.y + wt1 * a1.y + wt2 * a2.y + wt3 * a3.y;
  r.z = wt0 * a0.z + wt1 * a1.z + wt2 * a2.z + wt3 * a3.z;
  r.w = wt0 * a0.w + wt1 * a1.w + wt2 * a2.w + wt3 * a3.w;
  *(float4*)(c0part + ((size_t)sc * 32 + b) * 1024 + 4 * t) = r;
  if (t == 0) {
    msum_part[((size_t)sc * 32 + b) * 2 + 0] = mb;
    msum_part[((size_t)sc * 32 + b) * 2 + 1] = sb;
  }
}

// ---------------------------------------------------------------------------
// attn_finish: combine 32 chunk partials -> c0 (normalized), plus top-4 of
// the logits row -> scores/sent. grid 32 (b), block 256.
// ---------------------------------------------------------------------------
__device__ __forceinline__ bool vi_better(float av, int ai, float bv, int bi) {
  return av > bv || (av == bv && ai < bi);
}

__global__ __launch_bounds__(256) void attn_finish(
    const float* __restrict__ c0part, const float* __restrict__ msum_part,
    const float* __restrict__ logits, float* __restrict__ c0,
    float* __restrict__ scores, int* __restrict__ sent) {
  int b = blockIdx.x, t = threadIdx.x;
  // chunk weights (uniform)
  float m = -FLT_MAX;
  float ms[CH];
#pragma unroll
  for (int c = 0; c < CH; c++) {
    ms[c] = msum_part[((size_t)c * 32 + b) * 2 + 0];
    m = fmaxf(m, ms[c]);
  }
  float sum = 0.f;
  float wc[CH];
#pragma unroll
  for (int c = 0; c < CH; c++) {
    wc[c] = expf(ms[c] - m);
    sum += msum_part[((size_t)c * 32 + b) * 2 + 1] * wc[c];
  }
  float inv = 1.f / sum;
  float4 a = make_float4(0.f, 0.f, 0.f, 0.f);
#pragma unroll
  for (int c = 0; c < CH; c++) {
    float4 v = *(const float4*)(c0part + ((size_t)c * 32 + b) * 1024 + 4 * t);
    a.x += wc[c] * v.x; a.y += wc[c] * v.y;
    a.z += wc[c] * v.z; a.w += wc[c] * v.w;
  }
  a.x *= inv; a.y *= inv; a.z *= inv; a.w *= inv;
  *(float4*)(c0 + (size_t)b * HH + 4 * t) = a;

  // top-4: per-thread sorted-4 over 8 strided elements, then bitonic merges
  float tv0 = -FLT_MAX, tv1 = -FLT_MAX, tv2 = -FLT_MAX, tv3 = -FLT_MAX;
  int ti0 = INT_MAX, ti1 = INT_MAX, ti2 = INT_MAX, ti3 = INT_MAX;
#pragma unroll
  for (int it = 0; it < 8; it++) {
    int idx = it * 256 + t;
    float v = logits[(size_t)b * SS + idx];
    if (vi_better(v, idx, tv3, ti3)) {
      tv3 = v; ti3 = idx;
      if (vi_better(tv3, ti3, tv2, ti2)) { float fv = tv2; int fi = ti2; tv2 = tv3; ti2 = ti3; tv3 = fv; ti3 = fi; }
      if (vi_better(tv2, ti2, tv1, ti1)) { float fv = tv1; int fi = ti1; tv1 = tv2; ti1 = ti2; tv2 = fv; ti2 = fi; }
      if (vi_better(tv1, ti1, tv0, ti0)) { float fv = tv0; int fi = ti0; tv0 = tv1; ti0 = ti1; tv1 = fv; ti1 = fi; }
    }
  }
  __shared__ float sv[256][4];
  __shared__ int si[256][4];
  sv[t][0] = tv0; sv[t][1] = tv1; sv[t][2] = tv2; sv[t][3] = tv3;
  si[t][0] = ti0; si[t][1] = ti1; si[t][2] = ti2; si[t][3] = ti3;
  __syncthreads();
  for (int off = 128; off; off >>= 1) {
    if (t < off) {
      float bv0 = sv[t + off][0], bv1 = sv[t + off][1], bv2 = sv[t + off][2], bv3 = sv[t + off][3];
      int bi0 = si[t + off][0], bi1 = si[t + off][1], bi2 = si[t + off][2], bi3 = si[t + off][3];
      // bitonic merge stage: CE(a_k, b_{3-k}) keep winners
      float mv0, mv1, mv2, mv3; int mi0, mi1, mi2, mi3;
      if (vi_better(tv0, ti0, bv3, bi3)) { mv0 = tv0; mi0 = ti0; } else { mv0 = bv3; mi0 = bi3; }
      if (vi_better(tv1, ti1, bv2, bi2)) { mv1 = tv1; mi1 = ti1; } else { mv1 = bv2; mi1 = bi2; }
      if (vi_better(tv2, ti2, bv1, bi1)) { mv2 = tv2; mi2 = ti2; } else { mv2 = bv1; mi2 = bi1; }
      if (vi_better(tv3, ti3, bv0, bi0)) { mv3 = tv3; mi3 = ti3; } else { mv3 = bv0; mi3 = bi0; }
      // bitonic sort-4 (desc): CE(0,2) CE(1,3) CE(0,1) CE(2,3)
      if (!vi_better(mv0, mi0, mv2, mi2)) { float fv = mv0; int fi = mi0; mv0 = mv2; mi0 = mi2; mv2 = fv; mi2 = fi; }
      if (!vi_better(mv1, mi1, mv3, mi3)) { float fv = mv1; int fi = mi1; mv1 = mv3; mi1 = mi3; mv3 = fv; mi3 = fi; }
      if (!vi_better(mv0, mi0, mv1, mi1)) { float fv = mv0; int fi = mi0; mv0 = mv1; mi0 = mi1; mv1 = fv; mi1 = fi; }
      if (!vi_better(mv2, mi2, mv3, mi3)) { float fv = mv2; int fi = mi2; mv2 = mv3; mi2 = mi3; mv3 = fv; mi3 = fi; }
      tv0 = mv0; tv1 = mv1; tv2 = mv2; tv3 = mv3;
      ti0 = mi0; ti1 = mi1; ti2 = mi2; ti3 = mi3;
      sv[t][0] = tv0; sv[t][1] = tv1; sv[t][2] = tv2; sv[t][3] = tv3;
      si[t][0] = ti0; si[t][1] = ti1; si[t][2] = ti2; si[t][3] = ti3;
    }
    __syncthreads();
  }
  if (t == 0) {
    scores[b * KK + 0] = expf(tv0 - m) * inv; sent[b * KK + 0] = ti0;
    scores[b * KK + 1] = expf(tv1 - m) * inv; sent[b * KK + 1] = ti1;
    scores[b * KK + 2] = expf(tv2 - m) * inv; sent[b * KK + 2] = ti2;
    scores[b * KK + 3] = expf(tv3 - m) * inv; sent[b * KK + 3] = ti3;
  }
}

// ---------------------------------------------------------------------------
// ctxpart[(kc*32+b)*1024 + j] = sum_{k in chunk32} c0[b,k]*Wv[j,k]
// grid (2, 32), block 256; j = j0 + 2t, j0 + 2t + 1
// ---------------------------------------------------------------------------
__global__ __launch_bounds__(256) void ctx_partial(const float* __restrict__ c0,
                                                   const float* __restrict__ Wv,
                                                   float* __restrict__ part) {
  int t = threadIdx.x;
  int j0 = blockIdx.x * 512;
  int k0 = blockIdx.y * 32;
  const float* w1p = Wv + (size_t)(j0 + 2 * t) * HH + k0;
  const float* w2p = w1p + HH;
  float acc0[32], acc1[32];
#pragma unroll
  for (int b = 0; b < 32; b++) { acc0[b] = 0.f; acc1[b] = 0.f; }
  for (int kk = 0; kk < 32; kk += 4) {
    float4 w1 = *(const float4*)(w1p + kk);
    float4 w2 = *(const float4*)(w2p + kk);
#pragma unroll
    for (int b = 0; b < 32; b++) {
      float4 a = *(const float4*)(c0 + (size_t)b * HH + k0 + kk);  // uniform
      acc0[b] += a.x * w1.x + a.y * w1.y + a.z * w1.z + a.w * w1.w;
      acc1[b] += a.x * w2.x + a.y * w2.y + a.z * w2.z + a.w * w2.w;
    }
  }
  float* pb = part + (size_t)blockIdx.y * 32 * 1024 + j0 + 2 * t;
#pragma unroll
  for (int b = 0; b < 32; b++) {
    *(float2*)(pb + (size_t)b * 1024) = make_float2(acc0[b], acc1[b]);
  }
}

// ---------------------------------------------------------------------------
// Selection (recomputed per output block) + gather + ctx partial-reduce(+bv)
// grid 32 (output b), block 256
// ---------------------------------------------------------------------------
__global__ __launch_bounds__(256) void sel_gather(
    const float* __restrict__ scores, const int* __restrict__ sent,
    const float* __restrict__ evidence, const int* __restrict__ esi,
    const float* __restrict__ ctxpart, const float* __restrict__ bv,
    const float* __restrict__ hnew, const float* __restrict__ attn_in,
    const float* __restrict__ logits, const float* __restrict__ mask,
    float* __restrict__ out0, float* __restrict__ out1,
    float* __restrict__ out2, float* __restrict__ out3,
    float* __restrict__ out4, float* __restrict__ out5) {
  __shared__ int s_sh;
  int b = blockIdx.x, t = threadIdx.x;
  if (t == 0) {
    int r = b >> 2, j = b & 3;
    float ls[16];
    bool used[16];
    for (int k1 = 0; k1 < 4; k1++)
      for (int k2 = 0; k2 < 4; k2++)
        ls[k1 * 4 + k2] = -logf(scores[(r * 4 + k1) * 4 + k2]) + evidence[r * 4 + k1];
    for (int i = 0; i < 16; i++) used[i] = false;
    int best = 0;
    float bvv = FLT_MAX;
    for (int jj = 0; jj <= j; jj++) {
      best = 0;
      bvv = FLT_MAX;
      for (int i = 0; i < 16; i++)
        if (!used[i] && ls[i] < bvv) { bvv = ls[i]; best = i; }
      used[best] = true;
    }
    int k1 = best >> 2, k2 = best & 3;
    int sSel = r * 4 + k1;
    s_sh = sSel;
    out5[b] = bvv;
    out2[b * 3 + 0] = (float)esi[sSel * 2 + 0];
    out2[b * 3 + 1] = (float)esi[sSel * 2 + 1];
    out2[b * 3 + 2] = (float)sent[sSel * 4 + k2];
  }
  __syncthreads();
  int s = s_sh;
  {
    // result = ctx[s] = sum_kc ctxpart + bv
    float4 s0 = ((const float4*)bv)[t];
#pragma unroll
    for (int kc = 0; kc < 32; kc++) {
      float4 v = *(const float4*)(ctxpart + ((size_t)kc * 32 + s) * 1024 + 4 * t);
      s0.x += v.x; s0.y += v.y; s0.z += v.z; s0.w += v.w;
    }
    ((float4*)(out0 + (size_t)b * HH))[t] = s0;
    ((float4*)(out1 + (size_t)b * HH))[t] =
        ((const float4*)(hnew + (size_t)s * HH))[t];
  }
#pragma unroll
  for (int p = 0; p < 2; p++) {
    const float4* src = (const float4*)(attn_in + ((size_t)p * BB + s) * SS);
    float4* dst = (float4*)(out3 + ((size_t)p * BB + b) * SS);
    dst[t] = src[t];
    dst[t + 256] = src[t + 256];
  }
  {
    const float4* lg = (const float4*)(logits + (size_t)s * SS);
    float4* d2 = (float4*)(out3 + ((size_t)2 * BB + b) * SS);
    d2[t] = lg[t];
    d2[t + 256] = lg[t + 256];
    const float4* mk = (const float4*)(mask + (size_t)s * SS);
    float4* d4 = (float4*)(out4 + (size_t)b * SS);
    d4[t] = mk[t];
    d4[t + 256] = mk[t + 256];
  }
}

extern "C" void kernel_launch(void* const* d_in, const int* in_sizes, int n_in,
                              void* d_out, int out_size, void* d_ws, size_t ws_size,
                              hipStream_t stream) {
  const float* h_old = (const float*)d_in[0];
  const float* x     = (const float*)d_in[1];
  const float* eo    = (const float*)d_in[2];
  const float* attn_in = (const float*)d_in[3];
  const float* mask  = (const float*)d_in[4];
  const float* evidence = (const float*)d_in[5];
  const int*   esi   = (const int*)d_in[6];
  const float* W_ih  = (const float*)d_in[7];
  const float* W_hh  = (const float*)d_in[8];
  const float* b_ih  = (const float*)d_in[9];
  const float* b_hh  = (const float*)d_in[10];
  const float* Wk    = (const float*)d_in[11];
  const float* bk    = (const float*)d_in[12];
  const float* Wv    = (const float*)d_in[13];
  const float* bv    = (const float*)d_in[14];

  float* w = (float*)d_ws;
  float* h_new  = w + 0;         // 32768
  float* q      = w + 32768;     // 32768
  float* hbk    = w + 65536;     // 32
  float* logits = w + 65568;     // 65536
  float* scores = w + 131104;    // 128
  int*   sent   = (int*)(w + 131232);  // 128
  float* c0     = w + 131360;    // 32768
  float* msum_part = w + 164128; // 2048
  float* c0part = w + 166176;    // 1,048,576
  float* gpart  = w + 1214752;   // 3,145,728
  float* qpart  = w + 4360480;   // 524,288
  float* ctxpart= w + 4884768;   // 1,048,576

  float* out0 = (float*)d_out;   // result (32,1,1024)
  float* out1 = out0 + 32768;    // hidden (1,32,1024)
  float* out2 = out1 + 32768;    // new_evidence_sentence_index (32,3)
  float* out3 = out2 + 96;       // new_attention_scores (3,32,1,2048)
  float* out4 = out3 + 196608;   // new_attention_mask (32,1,2048)
  float* out5 = out4 + 65536;    // new_evidence_scores (32,)

  gates_partial<<<dim3(12, 16), 256, 0, stream>>>(x, h_old, W_ih, W_hh, gpart);
  gates_reduce_gru<<<128, 256, 0, stream>>>(gpart, b_ih, b_hh, h_old, h_new);
  q_partial<<<dim3(4, 16), 256, 0, stream>>>(h_new, Wk, qpart);
  q_reduce_hbk<<<129, 256, 0, stream>>>(qpart, h_new, bk, q, hbk);
  fused_attn<<<dim3(CH, BB), 256, 0, stream>>>(eo, q, hbk, mask, logits, c0part, msum_part);
  attn_finish<<<BB, 256, 0, stream>>>(c0part, msum_part, logits, c0, scores, sent);
  ctx_partial<<<dim3(2, 32), 256, 0, stream>>>(c0, Wv, ctxpart);
  sel_gather<<<BB, 256, 0, stream>>>(scores, sent, evidence, esi, ctxpart, bv,
                                     h_new, attn_in, logits, mask,
                                     out0, out1, out2, out3, out4, out5);
}

// Round 4
// 153.551 us; speedup vs baseline: 1.5635x; 1.5635x over previous
//
#include <hip/hip_runtime.h>
#include <hip/hip_bf16.h>
#include <cfloat>
#include <climits>
#include <cmath>

// Problem constants: B=32, S=2048, H=1024, K=4, PREV=2, R=8
#define BB 32
#define SS 2048
#define HH 1024
#define KK 4
#define CH 32  // s-chunks per batch row in fused_attn (64 rows each)

// ---------------------------------------------------------------------------
// gates partials: part[(kblk*32 + b)*6144 + j] = sum_{k in chunk64} A[b,k]*W[j,k]
// j in [0,3072): W_ih with A=x ; j in [3072,6144): W_hh with A=h_old
// grid (24, 16), block 256. One j-row per thread; acc[32] over b.
// W read once, lane-per-row; A wave-uniform (scalar loads).
// ---------------------------------------------------------------------------
__global__ __launch_bounds__(256) void gates_partial(
    const float* __restrict__ x, const float* __restrict__ h_old,
    const float* __restrict__ W_ih, const float* __restrict__ W_hh,
    float* __restrict__ part) {
  int t = threadIdx.x;
  int jb = blockIdx.x;       // 0..23
  int k0 = blockIdx.y * 64;  // k-chunk base
  bool second = (jb >= 12);
  const float* A = second ? h_old : x;
  const float* W = second ? W_hh : W_ih;
  int j0 = jb * 256;                  // global j base
  int jr = j0 - (second ? 3072 : 0);  // row base within W
  const float* wp = W + (size_t)(jr + t) * HH + k0;
  float acc[32];
#pragma unroll
  for (int b = 0; b < 32; b++) acc[b] = 0.f;
  for (int kk = 0; kk < 64; kk += 4) {
    float4 wv = *(const float4*)(wp + kk);
#pragma unroll
    for (int b = 0; b < 32; b++) {
      float4 a = *(const float4*)(A + (size_t)b * HH + k0 + kk);  // uniform
      acc[b] += a.x * wv.x + a.y * wv.y + a.z * wv.z + a.w * wv.w;
    }
  }
  float* pb = part + (size_t)blockIdx.y * (32 * 6144) + j0 + t;
#pragma unroll
  for (int b = 0; b < 32; b++) pb[(size_t)b * 6144] = acc[b];
}

// ---------------------------------------------------------------------------
// Reduce gate partials (16 k-chunks) + bias + GRU pointwise -> h_new
// grid 128 (b = blk>>2, h-tile = blk&3), block 256
// ---------------------------------------------------------------------------
__global__ __launch_bounds__(256) void gates_reduce_gru(
    const float* __restrict__ part, const float* __restrict__ b_ih,
    const float* __restrict__ b_hh, const float* __restrict__ h_old,
    float* __restrict__ h_new) {
  int t = threadIdx.x;
  int b = blockIdx.x >> 2;
  int h = (blockIdx.x & 3) * 256 + t;
  float s0 = 0.f, s1 = 0.f, s2 = 0.f, s3 = 0.f, s4 = 0.f, s5 = 0.f;
#pragma unroll
  for (int kc = 0; kc < 16; kc++) {
    const float* p = part + ((size_t)kc * 32 + b) * 6144;
    s0 += p[h];
    s1 += p[1024 + h];
    s2 += p[2048 + h];
    s3 += p[3072 + h];
    s4 += p[4096 + h];
    s5 += p[5120 + h];
  }
  float ir = s0 + b_ih[h], iz = s1 + b_ih[1024 + h], in_ = s2 + b_ih[2048 + h];
  float hr = s3 + b_hh[h], hz = s4 + b_hh[1024 + h], hn = s5 + b_hh[2048 + h];
  float r = 1.f / (1.f + expf(-(ir + hr)));
  float z = 1.f / (1.f + expf(-(iz + hz)));
  float n = tanhf(in_ + r * hn);
  h_new[b * HH + h] = (1.f - z) * n + z * h_old[b * HH + h];
}

// ---------------------------------------------------------------------------
// qpart[(kblk*32+b)*1024 + n] = sum_{k in chunk32} h_new[b,k] * Wk[k*H + n]
// grid (2, 32), block 256; each thread: 2 consecutive n (float2 Wk loads,
// coalesced), h_new wave-uniform.
// ---------------------------------------------------------------------------
__global__ __launch_bounds__(256) void q_partial(const float* __restrict__ hnew,
                                                 const float* __restrict__ Wk,
                                                 float* __restrict__ qpart) {
  int t = threadIdx.x;
  int n0 = blockIdx.x * 512 + 2 * t;
  int k0 = blockIdx.y * 32;
  float acc0[32], acc1[32];
#pragma unroll
  for (int b = 0; b < 32; b++) { acc0[b] = 0.f; acc1[b] = 0.f; }
  for (int k = 0; k < 32; k += 4) {
    float2 w0 = *(const float2*)(Wk + (size_t)(k0 + k) * HH + n0);
    float2 w1 = *(const float2*)(Wk + (size_t)(k0 + k + 1) * HH + n0);
    float2 w2 = *(const float2*)(Wk + (size_t)(k0 + k + 2) * HH + n0);
    float2 w3 = *(const float2*)(Wk + (size_t)(k0 + k + 3) * HH + n0);
#pragma unroll
    for (int b = 0; b < 32; b++) {
      float4 a = *(const float4*)(hnew + (size_t)b * HH + k0 + k);  // uniform
      acc0[b] += a.x * w0.x + a.y * w1.x + a.z * w2.x + a.w * w3.x;
      acc1[b] += a.x * w0.y + a.y * w1.y + a.z * w2.y + a.w * w3.y;
    }
  }
  float* pb = qpart + (size_t)blockIdx.y * (32 * 1024) + n0;
#pragma unroll
  for (int b = 0; b < 32; b++)
    *(float2*)(pb + (size_t)b * 1024) = make_float2(acc0[b], acc1[b]);
}

// blocks 0..127: q = sum of 32 k-chunk partials. block 128: hbk (wave-parallel)
__global__ __launch_bounds__(256) void q_reduce_hbk(
    const float* __restrict__ qpart, const float* __restrict__ hnew,
    const float* __restrict__ bk, float* __restrict__ q,
    float* __restrict__ hbk) {
  int t = threadIdx.x;
  if (blockIdx.x < 128) {
    int b = blockIdx.x >> 2;
    int n = (blockIdx.x & 3) * 256 + t;
    float s = 0.f;
#pragma unroll
    for (int kc = 0; kc < 32; kc++) s += qpart[((size_t)kc * 32 + b) * 1024 + n];
    q[b * HH + n] = s;
  } else {
    int w = t >> 6, lane = t & 63;
    const float4* bk4 = (const float4*)bk;
    float4 kv[4];
#pragma unroll
    for (int i = 0; i < 4; i++) kv[i] = bk4[i * 64 + lane];
    for (int b = w; b < BB; b += 4) {
      const float4* h4 = (const float4*)(hnew + (size_t)b * HH);
      float s = 0.f;
#pragma unroll
      for (int i = 0; i < 4; i++) {
        float4 hv = h4[i * 64 + lane];
        s += hv.x * kv[i].x + hv.y * kv[i].y + hv.z * kv[i].z + hv.w * kv[i].w;
      }
#pragma unroll
      for (int off = 32; off; off >>= 1) s += __shfl_xor(s, off);
      if (lane == 0) hbk[b] = s;
    }
  }
}

// ---------------------------------------------------------------------------
// Fused attention pass (single HBM read of eo), per-wave independent rows:
// wave w of block (sc,b) handles rows sc*64 + w*16 .. +15, 2 rows per tile
// (rv[2][4] keeps VGPR <= 128 -> 4 waves/SIMD via launch_bounds).
// ---------------------------------------------------------------------------
__global__ __launch_bounds__(256, 4) void fused_attn(
    const float* __restrict__ eo, const float* __restrict__ q,
    const float* __restrict__ hbk, const float* __restrict__ mask,
    float* __restrict__ logits, float* __restrict__ c0part,
    float* __restrict__ msum_part) {
  __shared__ float cacc[4][1024];
  __shared__ float cms[4][2];
  int b = blockIdx.y, sc = blockIdx.x, t = threadIdx.x;
  int w = t >> 6, lane = t & 63;
  const float4* q4 = (const float4*)(q + (size_t)b * HH);
  float4 qv[4];
#pragma unroll
  for (int i = 0; i < 4; i++) qv[i] = q4[i * 64 + lane];
  float hb = hbk[b];
  float m = -FLT_MAX, sum = 0.f;
  float4 acc[4];
#pragma unroll
  for (int i = 0; i < 4; i++) acc[i] = make_float4(0.f, 0.f, 0.f, 0.f);
  int rbase = sc * 64 + w * 16;
  for (int tile = 0; tile < 8; tile++) {
    int r0 = rbase + tile * 2;
    float4 rv[2][4];
#pragma unroll
    for (int rr = 0; rr < 2; rr++) {
      const float4* e4 = (const float4*)(eo + ((size_t)b * SS + r0 + rr) * HH);
#pragma unroll
      for (int i = 0; i < 4; i++) rv[rr][i] = e4[i * 64 + lane];
    }
    float p0 = 0.f, p1 = 0.f;
#pragma unroll
    for (int i = 0; i < 4; i++) {
      p0 += rv[0][i].x * qv[i].x + rv[0][i].y * qv[i].y +
            rv[0][i].z * qv[i].z + rv[0][i].w * qv[i].w;
      p1 += rv[1][i].x * qv[i].x + rv[1][i].y * qv[i].y +
            rv[1][i].z * qv[i].z + rv[1][i].w * qv[i].w;
    }
#pragma unroll
    for (int off = 32; off; off >>= 1) {
      p0 += __shfl_xor(p0, off);
      p1 += __shfl_xor(p1, off);
    }
    float lv0 = (p0 + hb) * 0.03125f + mask[(size_t)b * SS + r0];
    float lv1 = (p1 + hb) * 0.03125f + mask[(size_t)b * SS + r0 + 1];
    if (lane == 0) {
      logits[(size_t)b * SS + r0] = lv0;
      logits[(size_t)b * SS + r0 + 1] = lv1;
    }
    float m_new = fmaxf(m, fmaxf(lv0, lv1));
    float scale = expf(m - m_new);  // exp(-inf)=0 on first tile
    float w0 = expf(lv0 - m_new), w1 = expf(lv1 - m_new);
    sum = sum * scale + w0 + w1;
#pragma unroll
    for (int i = 0; i < 4; i++) {
      acc[i].x = acc[i].x * scale + w0 * rv[0][i].x + w1 * rv[1][i].x;
      acc[i].y = acc[i].y * scale + w0 * rv[0][i].y + w1 * rv[1][i].y;
      acc[i].z = acc[i].z * scale + w0 * rv[0][i].z + w1 * rv[1][i].z;
      acc[i].w = acc[i].w * scale + w0 * rv[0][i].w + w1 * rv[1][i].w;
    }
    m = m_new;
  }
  // block combine (one sync)
#pragma unroll
  for (int i = 0; i < 4; i++)
    *(float4*)&cacc[w][i * 256 + lane * 4] = acc[i];
  if (lane == 0) { cms[w][0] = m; cms[w][1] = sum; }
  __syncthreads();
  float m0 = cms[0][0], m1 = cms[1][0], m2 = cms[2][0], m3 = cms[3][0];
  float mb = fmaxf(fmaxf(m0, m1), fmaxf(m2, m3));
  float wt0 = expf(m0 - mb), wt1 = expf(m1 - mb), wt2 = expf(m2 - mb),
        wt3 = expf(m3 - mb);
  float sb = cms[0][1] * wt0 + cms[1][1] * wt1 + cms[2][1] * wt2 + cms[3][1] * wt3;
  float4 a0 = *(float4*)&cacc[0][4 * t];
  float4 a1 = *(float4*)&cacc[1][4 * t];
  float4 a2 = *(float4*)&cacc[2][4 * t];
  float4 a3 = *(float4*)&cacc[3][4 * t];
  float4 r;
  r.x = wt0 * a0.x + wt1 * a1.x + wt2 * a2.x + wt3 * a3.x;
  r.y = wt0 * a0.y + wt1 * a1.y + wt2 * a2.y + wt3 * a3.y;
  r.z = wt0 * a0.z + wt1 * a1.z + wt2 * a2.z + wt3 * a3.z;
  r.w = wt0 * a0.w + wt1 * a1.w + wt2 * a2.w + wt3 * a3.w;
  *(float4*)(c0part + ((size_t)sc * 32 + b) * 1024 + 4 * t) = r;
  if (t == 0) {
    msum_part[((size_t)sc * 32 + b) * 2 + 0] = mb;
    msum_part[((size_t)sc * 32 + b) * 2 + 1] = sb;
  }
}

// ---------------------------------------------------------------------------
// attn_finish: combine 32 chunk partials -> c0 (normalized), plus top-4 of
// the logits row -> scores/sent. grid 32 (b), block 256.
// ---------------------------------------------------------------------------
__device__ __forceinline__ bool vi_better(float av, int ai, float bv, int bi) {
  return av > bv || (av == bv && ai < bi);
}

__global__ __launch_bounds__(256) void attn_finish(
    const float* __restrict__ c0part, const float* __restrict__ msum_part,
    const float* __restrict__ logits, float* __restrict__ c0,
    float* __restrict__ scores, int* __restrict__ sent) {
  int b = blockIdx.x, t = threadIdx.x;
  float m = -FLT_MAX;
  float ms[CH];
#pragma unroll
  for (int c = 0; c < CH; c++) {
    ms[c] = msum_part[((size_t)c * 32 + b) * 2 + 0];
    m = fmaxf(m, ms[c]);
  }
  float sum = 0.f;
  float wc[CH];
#pragma unroll
  for (int c = 0; c < CH; c++) {
    wc[c] = expf(ms[c] - m);
    sum += msum_part[((size_t)c * 32 + b) * 2 + 1] * wc[c];
  }
  float inv = 1.f / sum;
  float4 a = make_float4(0.f, 0.f, 0.f, 0.f);
#pragma unroll
  for (int c = 0; c < CH; c++) {
    float4 v = *(const float4*)(c0part + ((size_t)c * 32 + b) * 1024 + 4 * t);
    a.x += wc[c] * v.x; a.y += wc[c] * v.y;
    a.z += wc[c] * v.z; a.w += wc[c] * v.w;
  }
  a.x *= inv; a.y *= inv; a.z *= inv; a.w *= inv;
  *(float4*)(c0 + (size_t)b * HH + 4 * t) = a;

  // top-4: per-thread sorted-4 over 8 strided elements, then bitonic merges
  float tv0 = -FLT_MAX, tv1 = -FLT_MAX, tv2 = -FLT_MAX, tv3 = -FLT_MAX;
  int ti0 = INT_MAX, ti1 = INT_MAX, ti2 = INT_MAX, ti3 = INT_MAX;
#pragma unroll
  for (int it = 0; it < 8; it++) {
    int idx = it * 256 + t;
    float v = logits[(size_t)b * SS + idx];
    if (vi_better(v, idx, tv3, ti3)) {
      tv3 = v; ti3 = idx;
      if (vi_better(tv3, ti3, tv2, ti2)) { float fv = tv2; int fi = ti2; tv2 = tv3; ti2 = ti3; tv3 = fv; ti3 = fi; }
      if (vi_better(tv2, ti2, tv1, ti1)) { float fv = tv1; int fi = ti1; tv1 = tv2; ti1 = ti2; tv2 = fv; ti2 = fi; }
      if (vi_better(tv1, ti1, tv0, ti0)) { float fv = tv0; int fi = ti0; tv0 = tv1; ti0 = ti1; tv1 = fv; ti1 = fi; }
    }
  }
  __shared__ float sv[256][4];
  __shared__ int si[256][4];
  sv[t][0] = tv0; sv[t][1] = tv1; sv[t][2] = tv2; sv[t][3] = tv3;
  si[t][0] = ti0; si[t][1] = ti1; si[t][2] = ti2; si[t][3] = ti3;
  __syncthreads();
  for (int off = 128; off; off >>= 1) {
    if (t < off) {
      float bv0 = sv[t + off][0], bv1 = sv[t + off][1], bv2 = sv[t + off][2], bv3 = sv[t + off][3];
      int bi0 = si[t + off][0], bi1 = si[t + off][1], bi2 = si[t + off][2], bi3 = si[t + off][3];
      float mv0, mv1, mv2, mv3; int mi0, mi1, mi2, mi3;
      if (vi_better(tv0, ti0, bv3, bi3)) { mv0 = tv0; mi0 = ti0; } else { mv0 = bv3; mi0 = bi3; }
      if (vi_better(tv1, ti1, bv2, bi2)) { mv1 = tv1; mi1 = ti1; } else { mv1 = bv2; mi1 = bi2; }
      if (vi_better(tv2, ti2, bv1, bi1)) { mv2 = tv2; mi2 = ti2; } else { mv2 = bv1; mi2 = bi1; }
      if (vi_better(tv3, ti3, bv0, bi0)) { mv3 = tv3; mi3 = ti3; } else { mv3 = bv0; mi3 = bi0; }
      if (!vi_better(mv0, mi0, mv2, mi2)) { float fv = mv0; int fi = mi0; mv0 = mv2; mi0 = mi2; mv2 = fv; mi2 = fi; }
      if (!vi_better(mv1, mi1, mv3, mi3)) { float fv = mv1; int fi = mi1; mv1 = mv3; mi1 = mi3; mv3 = fv; mi3 = fi; }
      if (!vi_better(mv0, mi0, mv1, mi1)) { float fv = mv0; int fi = mi0; mv0 = mv1; mi0 = mi1; mv1 = fv; mi1 = fi; }
      if (!vi_better(mv2, mi2, mv3, mi3)) { float fv = mv2; int fi = mi2; mv2 = mv3; mi2 = mi3; mv3 = fv; mi3 = fi; }
      tv0 = mv0; tv1 = mv1; tv2 = mv2; tv3 = mv3;
      ti0 = mi0; ti1 = mi1; ti2 = mi2; ti3 = mi3;
      sv[t][0] = tv0; sv[t][1] = tv1; sv[t][2] = tv2; sv[t][3] = tv3;
      si[t][0] = ti0; si[t][1] = ti1; si[t][2] = ti2; si[t][3] = ti3;
    }
    __syncthreads();
  }
  if (t == 0) {
    scores[b * KK + 0] = expf(tv0 - m) * inv; sent[b * KK + 0] = ti0;
    scores[b * KK + 1] = expf(tv1 - m) * inv; sent[b * KK + 1] = ti1;
    scores[b * KK + 2] = expf(tv2 - m) * inv; sent[b * KK + 2] = ti2;
    scores[b * KK + 3] = expf(tv3 - m) * inv; sent[b * KK + 3] = ti3;
  }
}

// ---------------------------------------------------------------------------
// ctxpart[(kblk*32+b)*1024 + j] = sum_{k in chunk32} c0[b,k]*Wv[j,k]
// grid (4, 32), block 256; one j-row per thread, acc[32] over b.
// ---------------------------------------------------------------------------
__global__ __launch_bounds__(256) void ctx_partial(const float* __restrict__ c0,
                                                   const float* __restrict__ Wv,
                                                   float* __restrict__ part) {
  int t = threadIdx.x;
  int j = blockIdx.x * 256 + t;
  int k0 = blockIdx.y * 32;
  const float* wp = Wv + (size_t)j * HH + k0;
  float acc[32];
#pragma unroll
  for (int b = 0; b < 32; b++) acc[b] = 0.f;
  for (int kk = 0; kk < 32; kk += 4) {
    float4 wv = *(const float4*)(wp + kk);
#pragma unroll
    for (int b = 0; b < 32; b++) {
      float4 a = *(const float4*)(c0 + (size_t)b * HH + k0 + kk);  // uniform
      acc[b] += a.x * wv.x + a.y * wv.y + a.z * wv.z + a.w * wv.w;
    }
  }
  float* pb = part + (size_t)blockIdx.y * (32 * 1024) + j;
#pragma unroll
  for (int b = 0; b < 32; b++) pb[(size_t)b * 1024] = acc[b];
}

// ---------------------------------------------------------------------------
// Selection (recomputed per output block) + gather + ctx partial-reduce(+bv)
// grid 32 (output b), block 256
// ---------------------------------------------------------------------------
__global__ __launch_bounds__(256) void sel_gather(
    const float* __restrict__ scores, const int* __restrict__ sent,
    const float* __restrict__ evidence, const int* __restrict__ esi,
    const float* __restrict__ ctxpart, const float* __restrict__ bv,
    const float* __restrict__ hnew, const float* __restrict__ attn_in,
    const float* __restrict__ logits, const float* __restrict__ mask,
    float* __restrict__ out0, float* __restrict__ out1,
    float* __restrict__ out2, float* __restrict__ out3,
    float* __restrict__ out4, float* __restrict__ out5) {
  __shared__ int s_sh;
  int b = blockIdx.x, t = threadIdx.x;
  if (t == 0) {
    int r = b >> 2, j = b & 3;
    float ls[16];
    bool used[16];
    for (int k1 = 0; k1 < 4; k1++)
      for (int k2 = 0; k2 < 4; k2++)
        ls[k1 * 4 + k2] = -logf(scores[(r * 4 + k1) * 4 + k2]) + evidence[r * 4 + k1];
    for (int i = 0; i < 16; i++) used[i] = false;
    int best = 0;
    float bvv = FLT_MAX;
    for (int jj = 0; jj <= j; jj++) {
      best = 0;
      bvv = FLT_MAX;
      for (int i = 0; i < 16; i++)
        if (!used[i] && ls[i] < bvv) { bvv = ls[i]; best = i; }
      used[best] = true;
    }
    int k1 = best >> 2, k2 = best & 3;
    int sSel = r * 4 + k1;
    s_sh = sSel;
    out5[b] = bvv;
    out2[b * 3 + 0] = (float)esi[sSel * 2 + 0];
    out2[b * 3 + 1] = (float)esi[sSel * 2 + 1];
    out2[b * 3 + 2] = (float)sent[sSel * 4 + k2];
  }
  __syncthreads();
  int s = s_sh;
  {
    // result = ctx[s] = sum_kblk ctxpart + bv
    float4 s0 = ((const float4*)bv)[t];
#pragma unroll
    for (int kc = 0; kc < 32; kc++) {
      float4 v = *(const float4*)(ctxpart + ((size_t)kc * 32 + s) * 1024 + 4 * t);
      s0.x += v.x; s0.y += v.y; s0.z += v.z; s0.w += v.w;
    }
    ((float4*)(out0 + (size_t)b * HH))[t] = s0;
    ((float4*)(out1 + (size_t)b * HH))[t] =
        ((const float4*)(hnew + (size_t)s * HH))[t];
  }
#pragma unroll
  for (int p = 0; p < 2; p++) {
    const float4* src = (const float4*)(attn_in + ((size_t)p * BB + s) * SS);
    float4* dst = (float4*)(out3 + ((size_t)p * BB + b) * SS);
    dst[t] = src[t];
    dst[t + 256] = src[t + 256];
  }
  {
    const float4* lg = (const float4*)(logits + (size_t)s * SS);
    float4* d2 = (float4*)(out3 + ((size_t)2 * BB + b) * SS);
    d2[t] = lg[t];
    d2[t + 256] = lg[t + 256];
    const float4* mk = (const float4*)(mask + (size_t)s * SS);
    float4* d4 = (float4*)(out4 + (size_t)b * SS);
    d4[t] = mk[t];
    d4[t + 256] = mk[t + 256];
  }
}

extern "C" void kernel_launch(void* const* d_in, const int* in_sizes, int n_in,
                              void* d_out, int out_size, void* d_ws, size_t ws_size,
                              hipStream_t stream) {
  const float* h_old = (const float*)d_in[0];
  const float* x     = (const float*)d_in[1];
  const float* eo    = (const float*)d_in[2];
  const float* attn_in = (const float*)d_in[3];
  const float* mask  = (const float*)d_in[4];
  const float* evidence = (const float*)d_in[5];
  const int*   esi   = (const int*)d_in[6];
  const float* W_ih  = (const float*)d_in[7];
  const float* W_hh  = (const float*)d_in[8];
  const float* b_ih  = (const float*)d_in[9];
  const float* b_hh  = (const float*)d_in[10];
  const float* Wk    = (const float*)d_in[11];
  const float* bk    = (const float*)d_in[12];
  const float* Wv    = (const float*)d_in[13];
  const float* bv    = (const float*)d_in[14];

  float* w = (float*)d_ws;
  float* h_new  = w + 0;         // 32768
  float* q      = w + 32768;     // 32768
  float* hbk    = w + 65536;     // 32
  float* logits = w + 65568;     // 65536
  float* scores = w + 131104;    // 128
  int*   sent   = (int*)(w + 131232);  // 128
  float* c0     = w + 131360;    // 32768
  float* msum_part = w + 164128; // 2048
  float* c0part = w + 166176;    // 1,048,576
  float* gpart  = w + 1214752;   // 3,145,728
  float* qpart  = w + 4360480;   // 1,048,576
  float* ctxpart= w + 5409056;   // 1,048,576

  float* out0 = (float*)d_out;   // result (32,1,1024)
  float* out1 = out0 + 32768;    // hidden (1,32,1024)
  float* out2 = out1 + 32768;    // new_evidence_sentence_index (32,3)
  float* out3 = out2 + 96;       // new_attention_scores (3,32,1,2048)
  float* out4 = out3 + 196608;   // new_attention_mask (32,1,2048)
  float* out5 = out4 + 65536;    // new_evidence_scores (32,)

  gates_partial<<<dim3(24, 16), 256, 0, stream>>>(x, h_old, W_ih, W_hh, gpart);
  gates_reduce_gru<<<128, 256, 0, stream>>>(gpart, b_ih, b_hh, h_old, h_new);
  q_partial<<<dim3(2, 32), 256, 0, stream>>>(h_new, Wk, qpart);
  q_reduce_hbk<<<129, 256, 0, stream>>>(qpart, h_new, bk, q, hbk);
  fused_attn<<<dim3(CH, BB), 256, 0, stream>>>(eo, q, hbk, mask, logits, c0part, msum_part);
  attn_finish<<<BB, 256, 0, stream>>>(c0part, msum_part, logits, c0, scores, sent);
  ctx_partial<<<dim3(4, 32), 256, 0, stream>>>(c0, Wv, ctxpart);
  sel_gather<<<BB, 256, 0, stream>>>(scores, sent, evidence, esi, ctxpart, bv,
                                     h_new, attn_in, logits, mask,
                                     out0, out1, out2, out3, out4, out5);
}